// Round 3
// baseline (33.317 us; speedup 1.0000x reference)
//
#include <hip/hip_runtime.h>
#include <math.h>

#define HB 16
#define CB 64
#define HH 128
#define WW 128
#define NFLOATS (HB * CB * HH * WW)   // 16,777,216

__global__ __launch_bounds__(256) void morpho_kernel(
    const float* __restrict__ x,     // [B,C,128,128]
    const float* __restrict__ w,     // [B,C,5,5]
    const float* __restrict__ bias,  // [B,C]
    const float* __restrict__ sign,  // [B]
    float* __restrict__ out)         // [B,C,128,128]
{
    const int blk  = blockIdx.x;
    const int quad = blk & 3;        // 32-row band
    const int bc   = blk >> 2;       // plane = b*64 + c
    const int b    = bc >> 6;

    float*       __restrict__ yp = out + (size_t)bc * (HH * WW);
    const float* __restrict__ wp = w   + bc * 25;

    const float sgn = sign[b];
    const float s   = (fabsf(sgn) >= 1e-7f) ? sgn : 1.0f;
    const float bv  = bias[bc];

    const int t  = threadIdx.x;
    const int tx = t & 31;           // col-block (4 cols)
    const int ty = t >> 5;           // 0..7
    const int j0 = tx * 4;
    const int i0 = quad * 32 + ty * 4;

    const int planeOff = bc * (HH * WW);
    const int rbase    = i0 - 2;

    // ---- pure load phase: all 24 loads issued before any tap math ----
    // Row clamped in-plane: out-of-range rows read garbage-but-in-bounds data
    // that is zeroed later via the sm multiplier (padding semantics).
    float4 v[8][3];
#pragma unroll
    for (int r8 = 0; r8 < 8; ++r8) {
        const int r  = rbase + r8;
        const int rc = min(max(r, 0), HH - 1);           // v_med3
        const int oM = planeOff + rc * WW + j0;
        const int oL = max(oM - 4, 0);                   // first-plane guard
        const int oR = min(oM + 4, NFLOATS - 4);         // last-plane guard
        v[r8][0] = *reinterpret_cast<const float4*>(x + oL);
        v[r8][1] = *reinterpret_cast<const float4*>(x + oM);
        v[r8][2] = *reinterpret_cast<const float4*>(x + oR);
    }

    // weights after the x loads so they don't delay the long-latency batch
    float wv[25];
#pragma unroll
    for (int k = 0; k < 25; ++k) wv[k] = wp[k];

    // col-padding multipliers (thread-constant)
    const float sL = (tx >= 1)  ? s : 0.f;
    const float sR = (tx <= 30) ? s : 0.f;

    float acc[4][4];                 // first-touch initialized at p==0

#pragma unroll
    for (int r8 = 0; r8 < 8; ++r8) {
        const int r  = rbase + r8;
        const bool rv = ((unsigned)r < (unsigned)HH);    // row padding
        const float smM = rv ? s  : 0.f;
        const float smL = rv ? sL : 0.f;
        const float smR = rv ? sR : 0.f;

        float xr[12];
        xr[0]  = v[r8][0].x * smL; xr[1]  = v[r8][0].y * smL;
        xr[2]  = v[r8][0].z * smL; xr[3]  = v[r8][0].w * smL;
        xr[4]  = v[r8][1].x * smM; xr[5]  = v[r8][1].y * smM;
        xr[6]  = v[r8][1].z * smM; xr[7]  = v[r8][1].w * smM;
        xr[8]  = v[r8][2].x * smR; xr[9]  = v[r8][2].y * smR;
        xr[10] = v[r8][2].z * smR; xr[11] = v[r8][2].w * smR;

#pragma unroll
        for (int p = 0; p < 5; ++p) {
            const int oi = r8 - p;   // output row in 4-row tile fed by this input row
            if (oi >= 0 && oi < 4) {
#pragma unroll
                for (int oj = 0; oj < 4; ++oj) {
                    // input col = j0 + oj + q - 2 -> xr index oj + q + 2
                    const float t0 = xr[oj + 2] + wv[p * 5 + 0];
                    const float t1 = xr[oj + 3] + wv[p * 5 + 1];
                    const float t2 = xr[oj + 4] + wv[p * 5 + 2];
                    const float t3 = xr[oj + 5] + wv[p * 5 + 3];
                    const float t4 = xr[oj + 6] + wv[p * 5 + 4];
                    float m;
                    if (p == 0) {
                        m = fmaxf(fmaxf(t0, t1), t2);   // -> v_max3
                        m = fmaxf(fmaxf(m, t3), t4);    // -> v_max3
                    } else {
                        m = acc[oi][oj];
                        m = fmaxf(fmaxf(m, t0), t1);    // -> v_max3
                        m = fmaxf(fmaxf(m, t2), t3);    // -> v_max3
                        m = fmaxf(m, t4);
                    }
                    acc[oi][oj] = m;
                }
            }
        }
    }

#pragma unroll
    for (int a = 0; a < 4; ++a) {
        float4 o;
        o.x = (acc[a][0] + bv) * s;
        o.y = (acc[a][1] + bv) * s;
        o.z = (acc[a][2] + bv) * s;
        o.w = (acc[a][3] + bv) * s;
        *reinterpret_cast<float4*>(yp + (size_t)(i0 + a) * WW + j0) = o;
    }
}

extern "C" void kernel_launch(void* const* d_in, const int* in_sizes, int n_in,
                              void* d_out, int out_size, void* d_ws, size_t ws_size,
                              hipStream_t stream) {
    const float* x    = (const float*)d_in[0];
    const float* w    = (const float*)d_in[1];
    const float* bias = (const float*)d_in[2];
    const float* sign = (const float*)d_in[3];
    float* out = (float*)d_out;

    const int planes = HB * CB;      // 1024
    const int grid   = planes * 4;   // 4 row-bands per plane
    morpho_kernel<<<grid, 256, 0, stream>>>(x, w, bias, sign, out);
}